// Round 1
// baseline (695.890 us; speedup 1.0000x reference)
//
#include <hip/hip_runtime.h>

#define AS1 __attribute__((address_space(1)))
#define AS3 __attribute__((address_space(3)))

typedef float f32x4 __attribute__((ext_vector_type(4)));
typedef __bf16 bf16x8 __attribute__((ext_vector_type(8)));

// fp32 -> bf16, round-to-nearest-even
__device__ __forceinline__ unsigned short f2bf(float f) {
  unsigned int u = __float_as_uint(f);
  u += 0x7fffu + ((u >> 16) & 1u);
  return (unsigned short)(u >> 16);
}

// ---------------------------------------------------------------------------
// Pass 1: transpose x [B][C][H][W] fp32 -> xt [B][H][W][C] bf16, fused with
// global-average-pool partial sums (atomicAdd into pooled[b][c], zeroed by host
// side memset each launch).
// Grid: B*H blocks (one (b,h) slice = 128x128 transpose), 256 threads.
// ---------------------------------------------------------------------------
__global__ __launch_bounds__(256) void prep_kernel(const float* __restrict__ x,
                                                   unsigned short* __restrict__ xt,
                                                   float* __restrict__ pooled) {
  // tile[w][c], stride 130 elements: scalar transposed writes (~4-way bank ok),
  // dword-aligned vector-ish reads, conflict-free enough.
  __shared__ __align__(16) unsigned short tile[128 * 130];
  const int bid = blockIdx.x;
  const int b = bid >> 7, hh = bid & 127;
  const int tid = threadIdx.x;
  const int wq = tid & 31;   // float4 index along w
  const int c8 = tid >> 5;   // 0..7
  const size_t xoff_bh = (size_t)b * (128 * 16384) + (size_t)hh * 128;
#pragma unroll
  for (int i = 0; i < 16; ++i) {
    const int c = i * 8 + c8;
    const float4 v = *(const float4*)(x + xoff_bh + (size_t)c * 16384 + wq * 4);
    const int w0 = wq * 4;
    tile[(w0 + 0) * 130 + c] = f2bf(v.x);
    tile[(w0 + 1) * 130 + c] = f2bf(v.y);
    tile[(w0 + 2) * 130 + c] = f2bf(v.z);
    tile[(w0 + 3) * 130 + c] = f2bf(v.w);
    float s = v.x + v.y + v.z + v.w;
    s += __shfl_down(s, 16, 32);
    s += __shfl_down(s, 8, 32);
    s += __shfl_down(s, 4, 32);
    s += __shfl_down(s, 2, 32);
    s += __shfl_down(s, 1, 32);
    if (wq == 0) atomicAdd(pooled + b * 128 + c, s);
  }
  __syncthreads();
  const int cq = tid & 15, w16 = tid >> 4;
  const size_t xtoff = (size_t)(b * 128 + hh) * 16384;
#pragma unroll
  for (int i = 0; i < 8; ++i) {
    const int w = i * 16 + w16;
    const unsigned short* tp = tile + w * 130 + cq * 8;
    uint4 v;
    v.x = *(const unsigned int*)(tp + 0);
    v.y = *(const unsigned int*)(tp + 2);
    v.z = *(const unsigned int*)(tp + 4);
    v.w = *(const unsigned int*)(tp + 6);
    *(uint4*)(xt + xtoff + (size_t)w * 128 + cq * 8) = v;
  }
}

// ---------------------------------------------------------------------------
// Pass 2: attention (softmax over K=4) computed redundantly per thread, then
// aggregate weights -> aggw[b][r*3+s][o][c] (bf16) and bias -> aggb[b][o].
// Grid: 32 blocks (one per sample), 256 threads.
// ---------------------------------------------------------------------------
__global__ __launch_bounds__(256) void attn_agg_kernel(
    const float* __restrict__ pooled, const float* __restrict__ w1,
    const float* __restrict__ b1, const float* __restrict__ w2,
    const float* __restrict__ b2, const float* __restrict__ weight,
    const float* __restrict__ bias, unsigned short* __restrict__ aggw,
    float* __restrict__ aggb) {
  const int b = blockIdx.x, tid = threadIdx.x;
  float att[4];
  {
    float hv[4];
#pragma unroll
    for (int k = 0; k < 4; ++k) {
      float s = b1[k];
      for (int c = 0; c < 128; ++c)
        s += pooled[b * 128 + c] * (1.0f / 16384.0f) * w1[k * 128 + c];
      hv[k] = fmaxf(s, 0.0f);
    }
    float lg[4], m = -1e30f;
#pragma unroll
    for (int j = 0; j < 4; ++j) {
      float s = b2[j];
#pragma unroll
      for (int k = 0; k < 4; ++k) s += hv[k] * w2[j * 4 + k];
      lg[j] = s;
      m = fmaxf(m, s);
    }
    float tot = 0.f;
#pragma unroll
    for (int j = 0; j < 4; ++j) {
      att[j] = __expf(lg[j] - m);
      tot += att[j];
    }
#pragma unroll
    for (int j = 0; j < 4; ++j) att[j] /= tot;
  }
  if (tid < 128) {
    float s = 0.f;
#pragma unroll
    for (int k = 0; k < 4; ++k) s += att[k] * bias[k * 128 + tid];
    aggb[b * 128 + tid] = s;
  }
  for (int idx = tid; idx < 16384; idx += 256) {
    float a9[9] = {0, 0, 0, 0, 0, 0, 0, 0, 0};
#pragma unroll
    for (int k = 0; k < 4; ++k) {
      const float* wp = weight + (size_t)(k * 16384 + idx) * 9;
      const float ak = att[k];
#pragma unroll
      for (int rs = 0; rs < 9; ++rs) a9[rs] += ak * wp[rs];
    }
#pragma unroll
    for (int rs = 0; rs < 9; ++rs)
      aggw[(size_t)(b * 9 + rs) * 16384 + idx] = f2bf(a9[rs]);
  }
}

// ---------------------------------------------------------------------------
// Pass 3: implicit-GEMM conv. One block per (b,h): C tile 128(O) x 128(W).
// A = aggw[b][rs] (128x128, [o][c]); B = xt[b][h+r-1] shifted window ([w][c]).
// mfma_f32_16x16x32_bf16; 4 waves in 2x2, each 4x4 of 16x16 tiles.
// LDS: XT 130x128 bf16 (rows 0/129 = zero halo -> padding for free) = 33280 B,
//      AB 128x64 bf16 (c-half of A) = 16384 B. Total 49664 B -> 3 blocks/CU.
// 16B-chunk XOR swizzle (cq ^= row) keeps global_load_lds contiguous AND
// makes fragment ds_read_b128 bank-conflict-free.
// ---------------------------------------------------------------------------
__device__ __forceinline__ void stage_xt(const char* g0, char* XT, int lane, int wv) {
  // 2048 chunks of 16B -> physical rows 1..128 (16 chunks per row)
#pragma unroll
  for (int i = 0; i < 8; ++i) {
    const int Lb = i * 256 + wv * 64;
    const int L = Lb + lane;
    const int row = L >> 4;                       // source w row 0..127
    const int cq = (L & 15) ^ ((row + 1) & 15);   // swizzle by PHYSICAL row
    __builtin_amdgcn_global_load_lds((AS1 void*)(g0 + row * 256 + cq * 16),
                                     (AS3 void*)(XT + 256 + Lb * 16), 16, 0, 0);
  }
}

__device__ __forceinline__ void stage_a_half(const char* g, char* AB, int ch,
                                             int lane, int wv) {
  const char* g0 = g + ch * 128;  // byte offset of c-half within 256B rows
#pragma unroll
  for (int i = 0; i < 4; ++i) {
    const int Lb = i * 256 + wv * 64;
    const int L = Lb + lane;
    const int row = L >> 3;            // o row 0..127 (8 chunks per row)
    const int cq = (L & 7) ^ (row & 7);
    __builtin_amdgcn_global_load_lds((AS1 void*)(g0 + row * 256 + cq * 16),
                                     (AS3 void*)(AB + Lb * 16), 16, 0, 0);
  }
}

__global__ __launch_bounds__(256, 3) void conv_kernel(
    const unsigned short* __restrict__ xt, const unsigned short* __restrict__ aggw,
    const float* __restrict__ aggb, float* __restrict__ out) {
  __shared__ __align__(16) char lds[130 * 256 + 128 * 128];
  char* XT = lds;           // 33280 B
  char* AB = lds + 33280;   // 16384 B

  const int bid = blockIdx.x;
  // XCD swizzle: 16 consecutive h per XCD per b -> L2 reuse of xt rows (3x)
  const int xc = bid & 7, g = bid >> 3;
  const int h = xc * 16 + (g & 15);
  const int b = g >> 4;

  const int tid = threadIdx.x;
  const int lane = tid & 63, wv = tid >> 6;
  const int wm = wv & 1, wn = wv >> 1;
  const int rlo = lane & 15, kg = lane >> 4;

  f32x4 acc[4][4] = {};

  // zero halo rows 0 and 129 (w = -1 and w = 128)
  if (tid < 128) {
    const int rr = (tid >> 6) ? 129 : 0;
    ((float*)(XT + rr * 256))[tid & 63] = 0.f;
  }

  const char* xb = (const char*)xt + (size_t)(b * 128) * 32768;
  const char* ab = (const char*)aggw + (size_t)(b * 9) * 32768;

  for (int r = 0; r < 3; ++r) {
    const int hr = h + r - 1;
    if (hr < 0 || hr >= 128) continue;  // zero row padding: skip (block-uniform)
    __syncthreads();  // prior readers of XT/AB done
    stage_xt(xb + (size_t)hr * 32768, XT, lane, wv);
    stage_a_half(ab + (size_t)(r * 3) * 32768, AB, 0, lane, wv);
    __syncthreads();
    for (int s = 0; s < 3; ++s) {
#pragma unroll
      for (int ch = 0; ch < 2; ++ch) {
#pragma unroll
        for (int kkl = 0; kkl < 2; ++kkl) {
          bf16x8 af[4], bfv[4];
#pragma unroll
          for (int mt = 0; mt < 4; ++mt) {
            const int row = wm * 64 + mt * 16 + rlo;
            const int cc = kkl * 4 + kg;
            af[mt] = *(const bf16x8*)(AB + row * 128 + ((cc ^ (row & 7)) << 4));
          }
#pragma unroll
          for (int nt = 0; nt < 4; ++nt) {
            const int p = wn * 64 + nt * 16 + rlo + s;  // physical row = w + s
            const int cc = ch * 8 + kkl * 4 + kg;
            bfv[nt] = *(const bf16x8*)(XT + p * 256 + ((cc ^ (p & 15)) << 4));
          }
#pragma unroll
          for (int mt = 0; mt < 4; ++mt)
#pragma unroll
            for (int nt = 0; nt < 4; ++nt)
              acc[mt][nt] = __builtin_amdgcn_mfma_f32_16x16x32_bf16(
                  af[mt], bfv[nt], acc[mt][nt], 0, 0, 0);
        }
        if (!((s == 2) && (ch == 1))) {
          const int ns = ch ? s + 1 : s;
          const int nch = ch ^ 1;
          __syncthreads();  // compute on AB done before restage
          stage_a_half(ab + (size_t)(r * 3 + ns) * 32768, AB, nch, lane, wv);
          __syncthreads();
        }
      }
    }
  }

  // epilogue: C/D layout col=lane&15 (w), row=(lane>>4)*4+i (o)
  const float* bb = aggb + b * 128;
  float* ob = out + (size_t)b * (128 * 16384) + h * 128;
#pragma unroll
  for (int mt = 0; mt < 4; ++mt) {
    const int o0 = wm * 64 + mt * 16 + kg * 4;
#pragma unroll
    for (int i = 0; i < 4; ++i) {
      const float bs = bb[o0 + i];
#pragma unroll
      for (int nt = 0; nt < 4; ++nt) {
        const int w = wn * 64 + nt * 16 + rlo;
        ob[(size_t)(o0 + i) * 16384 + w] = acc[mt][nt][i] + bs;
      }
    }
  }
}

// ---------------------------------------------------------------------------
extern "C" void kernel_launch(void* const* d_in, const int* in_sizes, int n_in,
                              void* d_out, int out_size, void* d_ws, size_t ws_size,
                              hipStream_t stream) {
  const float* x = (const float*)d_in[0];
  const float* w1 = (const float*)d_in[1];
  const float* b1 = (const float*)d_in[2];
  const float* w2 = (const float*)d_in[3];
  const float* b2 = (const float*)d_in[4];
  const float* wgt = (const float*)d_in[5];
  const float* bias = (const float*)d_in[6];
  float* out = (float*)d_out;

  char* ws = (char*)d_ws;
  unsigned short* xt = (unsigned short*)ws;                        // 134217728 B
  unsigned short* aggw = (unsigned short*)(ws + 134217728ull);     // 9437184 B
  float* pooled = (float*)(ws + 134217728ull + 9437184ull);        // 16384 B
  float* aggb = (float*)(ws + 134217728ull + 9437184ull + 16384ull);  // 16384 B

  hipMemsetAsync(pooled, 0, 32 * 128 * sizeof(float), stream);
  prep_kernel<<<4096, 256, 0, stream>>>(x, xt, pooled);
  attn_agg_kernel<<<32, 256, 0, stream>>>(pooled, w1, b1, w2, b2, wgt, bias,
                                          aggw, aggb);
  conv_kernel<<<4096, 256, 0, stream>>>(xt, aggw, aggb, out);
}

// Round 2
// 597.031 us; speedup vs baseline: 1.1656x; 1.1656x over previous
//
#include <hip/hip_runtime.h>

#define AS1 __attribute__((address_space(1)))
#define AS3 __attribute__((address_space(3)))

typedef float f32x4 __attribute__((ext_vector_type(4)));
typedef __bf16 bf16x8 __attribute__((ext_vector_type(8)));

// fp32 -> bf16, round-to-nearest-even
__device__ __forceinline__ unsigned short f2bf(float f) {
  unsigned int u = __float_as_uint(f);
  u += 0x7fffu + ((u >> 16) & 1u);
  return (unsigned short)(u >> 16);
}

__device__ __forceinline__ float bflo(unsigned int d) {
  return __uint_as_float(d << 16);
}
__device__ __forceinline__ float bfhi(unsigned int d) {
  return __uint_as_float(d & 0xffff0000u);
}

// ---------------------------------------------------------------------------
// Pass 1: transpose x [B][C][H][W] fp32 -> xt [B][H][W][C] bf16, fused with
// global-average-pool (from the bf16-rounded values; error ~1e-4, fine).
// Grid: B*H = 4096 blocks, 256 threads.
// Phase A: 16 float4 loads hoisted (latency!), pack (c,c+1) bf16 pairs,
//          swizzled ds_write_b32 (conflict-free: chunk ^= (w^(w>>2))&15 is a
//          permutation over each instruction's lanes).
// Phase B: ds_read_b128 -> global uint4 store (coalesced 256B/16 lanes),
//          fused pooling accumulation + xor-shuffle fold + 128 atomics/block.
// LDS: tile 32 KB + buf 2 KB -> 4 blocks/CU.
// ---------------------------------------------------------------------------
__global__ __launch_bounds__(256) void prep_kernel(const float* __restrict__ x,
                                                   unsigned short* __restrict__ xt,
                                                   float* __restrict__ pooled) {
  __shared__ __align__(16) unsigned int tile[128 * 64];
  __shared__ float buf[4 * 128];
  const int bid = blockIdx.x;
  const int b = bid >> 7, hh = bid & 127;
  const int tid = threadIdx.x;

  // ---- Phase A: load + pack + LDS write ----
  const int wq = tid & 31;   // w quad: w0 = wq*4
  const int c2b = tid >> 5;  // 0..7
  const size_t xoff_bh = (size_t)b * (128 * 16384) + (size_t)hh * 128;

  float4 va[8], vb[8];
#pragma unroll
  for (int i = 0; i < 8; ++i) {
    const int c2 = i * 8 + c2b;
    va[i] = *(const float4*)(x + xoff_bh + (size_t)(2 * c2) * 16384 + wq * 4);
    vb[i] = *(const float4*)(x + xoff_bh + (size_t)(2 * c2 + 1) * 16384 + wq * 4);
  }
#pragma unroll
  for (int i = 0; i < 8; ++i) {
    const int c2 = i * 8 + c2b;
    const int q = c2 >> 2, cl = c2 & 3;
    const float* pa = (const float*)&va[i];
    const float* pb = (const float*)&vb[i];
#pragma unroll
    for (int j = 0; j < 4; ++j) {
      const int w = wq * 4 + j;
      const int sw = (w ^ (w >> 2)) & 15;
      const unsigned int d =
          (unsigned int)f2bf(pa[j]) | ((unsigned int)f2bf(pb[j]) << 16);
      tile[w * 64 + ((q ^ sw) << 2) + cl] = d;
    }
  }
  __syncthreads();

  // ---- Phase B: LDS read (b128) -> global store, fused pooling ----
  const int q = tid & 15, w16 = tid >> 4;  // w16 in 0..15
  const size_t xtoff = (size_t)(b * 128 + hh) * 16384;
  float acc[8] = {0, 0, 0, 0, 0, 0, 0, 0};
#pragma unroll
  for (int i = 0; i < 8; ++i) {
    const int w = i * 16 + w16;
    const int sw = (w ^ (w >> 2)) & 15;
    const uint4 v = *(const uint4*)(tile + w * 64 + ((q ^ sw) << 2));
    *(uint4*)(xt + xtoff + (size_t)w * 128 + q * 8) = v;
    acc[0] += bflo(v.x); acc[1] += bfhi(v.x);
    acc[2] += bflo(v.y); acc[3] += bfhi(v.y);
    acc[4] += bflo(v.z); acc[5] += bfhi(v.z);
    acc[6] += bflo(v.w); acc[7] += bfhi(v.w);
  }
  // fold lanes sharing q (lane ^ 16, lane ^ 32)
#pragma unroll
  for (int j = 0; j < 8; ++j) {
    acc[j] += __shfl_xor(acc[j], 16, 64);
    acc[j] += __shfl_xor(acc[j], 32, 64);
  }
  const int lane = tid & 63, wv = tid >> 6;
  if (lane < 16) {
#pragma unroll
    for (int j = 0; j < 8; ++j) buf[wv * 128 + q * 8 + j] = acc[j];
  }
  __syncthreads();
  if (tid < 128) {
    const float s = buf[tid] + buf[128 + tid] + buf[256 + tid] + buf[384 + tid];
    atomicAdd(pooled + b * 128 + tid, s);
  }
}

// ---------------------------------------------------------------------------
// Pass 2: attention (softmax over K=4) computed redundantly per block, then
// aggregate weights -> aggw[b][r*3+s][o][c] (bf16) and bias -> aggb[b][o].
// Grid: 256 blocks = (b, slice of 2048 idx), 256 threads.
// ---------------------------------------------------------------------------
__global__ __launch_bounds__(256) void attn_agg_kernel(
    const float* __restrict__ pooled, const float* __restrict__ w1,
    const float* __restrict__ b1, const float* __restrict__ w2,
    const float* __restrict__ b2, const float* __restrict__ weight,
    const float* __restrict__ bias, unsigned short* __restrict__ aggw,
    float* __restrict__ aggb) {
  const int b = blockIdx.x >> 3, slice = blockIdx.x & 7;
  const int tid = threadIdx.x;
  float att[4];
  {
    float hv[4];
#pragma unroll
    for (int k = 0; k < 4; ++k) {
      float s = b1[k];
      for (int c = 0; c < 128; ++c)
        s += pooled[b * 128 + c] * (1.0f / 16384.0f) * w1[k * 128 + c];
      hv[k] = fmaxf(s, 0.0f);
    }
    float lg[4], m = -1e30f;
#pragma unroll
    for (int j = 0; j < 4; ++j) {
      float s = b2[j];
#pragma unroll
      for (int k = 0; k < 4; ++k) s += hv[k] * w2[j * 4 + k];
      lg[j] = s;
      m = fmaxf(m, s);
    }
    float tot = 0.f;
#pragma unroll
    for (int j = 0; j < 4; ++j) {
      att[j] = __expf(lg[j] - m);
      tot += att[j];
    }
#pragma unroll
    for (int j = 0; j < 4; ++j) att[j] /= tot;
  }
  if (slice == 0 && tid < 128) {
    float s = 0.f;
#pragma unroll
    for (int k = 0; k < 4; ++k) s += att[k] * bias[k * 128 + tid];
    aggb[b * 128 + tid] = s;
  }
#pragma unroll
  for (int j = 0; j < 8; ++j) {
    const int idx = slice * 2048 + j * 256 + tid;
    float a9[9] = {0, 0, 0, 0, 0, 0, 0, 0, 0};
#pragma unroll
    for (int k = 0; k < 4; ++k) {
      const float* wp = weight + (size_t)(k * 16384 + idx) * 9;
      const float ak = att[k];
#pragma unroll
      for (int rs = 0; rs < 9; ++rs) a9[rs] += ak * wp[rs];
    }
#pragma unroll
    for (int rs = 0; rs < 9; ++rs)
      aggw[(size_t)(b * 9 + rs) * 16384 + idx] = f2bf(a9[rs]);
  }
}

// ---------------------------------------------------------------------------
// Pass 3: implicit-GEMM conv. One block per (b,h): C tile 128(O) x 128(W).
// A = aggw[b][rs] (128x128, [o][c]); B = xt[b][h+r-1] shifted window ([w][c]).
// mfma_f32_16x16x32_bf16; 4 waves in 2x2, each 4x4 of 16x16 tiles.
// LDS: XT 130x256B (rows 0/129 zero halo = free w-padding) + AB 16 KB half-A.
// ---------------------------------------------------------------------------
__device__ __forceinline__ void stage_xt(const char* g0, char* XT, int lane, int wv) {
#pragma unroll
  for (int i = 0; i < 8; ++i) {
    const int Lb = i * 256 + wv * 64;
    const int L = Lb + lane;
    const int row = L >> 4;                       // source w row 0..127
    const int cq = (L & 15) ^ ((row + 1) & 15);   // swizzle by PHYSICAL row
    __builtin_amdgcn_global_load_lds((AS1 void*)(g0 + row * 256 + cq * 16),
                                     (AS3 void*)(XT + 256 + Lb * 16), 16, 0, 0);
  }
}

__device__ __forceinline__ void stage_a_half(const char* g, char* AB, int ch,
                                             int lane, int wv) {
  const char* g0 = g + ch * 128;  // byte offset of c-half within 256B rows
#pragma unroll
  for (int i = 0; i < 4; ++i) {
    const int Lb = i * 256 + wv * 64;
    const int L = Lb + lane;
    const int row = L >> 3;            // o row 0..127 (8 chunks per row)
    const int cq = (L & 7) ^ (row & 7);
    __builtin_amdgcn_global_load_lds((AS1 void*)(g0 + row * 256 + cq * 16),
                                     (AS3 void*)(AB + Lb * 16), 16, 0, 0);
  }
}

__global__ __launch_bounds__(256, 3) void conv_kernel(
    const unsigned short* __restrict__ xt, const unsigned short* __restrict__ aggw,
    const float* __restrict__ aggb, float* __restrict__ out) {
  __shared__ __align__(16) char lds[130 * 256 + 128 * 128];
  char* XT = lds;           // 33280 B
  char* AB = lds + 33280;   // 16384 B

  const int bid = blockIdx.x;
  // XCD swizzle: 16 consecutive h per XCD per b -> L2 reuse of xt rows (3x)
  const int xc = bid & 7, g = bid >> 3;
  const int h = xc * 16 + (g & 15);
  const int b = g >> 4;

  const int tid = threadIdx.x;
  const int lane = tid & 63, wv = tid >> 6;
  const int wm = wv & 1, wn = wv >> 1;
  const int rlo = lane & 15, kg = lane >> 4;

  f32x4 acc[4][4] = {};

  // zero halo rows 0 and 129 (w = -1 and w = 128)
  if (tid < 128) {
    const int rr = (tid >> 6) ? 129 : 0;
    ((float*)(XT + rr * 256))[tid & 63] = 0.f;
  }

  const char* xb = (const char*)xt + (size_t)(b * 128) * 32768;
  const char* ab = (const char*)aggw + (size_t)(b * 9) * 32768;

  for (int r = 0; r < 3; ++r) {
    const int hr = h + r - 1;
    if (hr < 0 || hr >= 128) continue;  // zero row padding: skip (block-uniform)
    __syncthreads();  // prior readers of XT/AB done
    stage_xt(xb + (size_t)hr * 32768, XT, lane, wv);
    stage_a_half(ab + (size_t)(r * 3) * 32768, AB, 0, lane, wv);
    __syncthreads();
    for (int s = 0; s < 3; ++s) {
#pragma unroll
      for (int ch = 0; ch < 2; ++ch) {
#pragma unroll
        for (int kkl = 0; kkl < 2; ++kkl) {
          bf16x8 af[4], bfv[4];
#pragma unroll
          for (int mt = 0; mt < 4; ++mt) {
            const int row = wm * 64 + mt * 16 + rlo;
            const int cc = kkl * 4 + kg;
            af[mt] = *(const bf16x8*)(AB + row * 128 + ((cc ^ (row & 7)) << 4));
          }
#pragma unroll
          for (int nt = 0; nt < 4; ++nt) {
            const int p = wn * 64 + nt * 16 + rlo + s;  // physical row = w + s
            const int cc = ch * 8 + kkl * 4 + kg;
            bfv[nt] = *(const bf16x8*)(XT + p * 256 + ((cc ^ (p & 15)) << 4));
          }
#pragma unroll
          for (int mt = 0; mt < 4; ++mt)
#pragma unroll
            for (int nt = 0; nt < 4; ++nt)
              acc[mt][nt] = __builtin_amdgcn_mfma_f32_16x16x32_bf16(
                  af[mt], bfv[nt], acc[mt][nt], 0, 0, 0);
        }
        if (!((s == 2) && (ch == 1))) {
          const int ns = ch ? s + 1 : s;
          const int nch = ch ^ 1;
          __syncthreads();  // compute on AB done before restage
          stage_a_half(ab + (size_t)(r * 3 + ns) * 32768, AB, nch, lane, wv);
          __syncthreads();
        }
      }
    }
  }

  // epilogue: C/D layout col=lane&15 (w), row=(lane>>4)*4+i (o)
  const float* bb = aggb + b * 128;
  float* ob = out + (size_t)b * (128 * 16384) + h * 128;
#pragma unroll
  for (int mt = 0; mt < 4; ++mt) {
    const int o0 = wm * 64 + mt * 16 + kg * 4;
#pragma unroll
    for (int i = 0; i < 4; ++i) {
      const float bs = bb[o0 + i];
#pragma unroll
      for (int nt = 0; nt < 4; ++nt) {
        const int w = wn * 64 + nt * 16 + rlo;
        ob[(size_t)(o0 + i) * 16384 + w] = acc[mt][nt][i] + bs;
      }
    }
  }
}

// ---------------------------------------------------------------------------
extern "C" void kernel_launch(void* const* d_in, const int* in_sizes, int n_in,
                              void* d_out, int out_size, void* d_ws, size_t ws_size,
                              hipStream_t stream) {
  const float* x = (const float*)d_in[0];
  const float* w1 = (const float*)d_in[1];
  const float* b1 = (const float*)d_in[2];
  const float* w2 = (const float*)d_in[3];
  const float* b2 = (const float*)d_in[4];
  const float* wgt = (const float*)d_in[5];
  const float* bias = (const float*)d_in[6];
  float* out = (float*)d_out;

  char* ws = (char*)d_ws;
  unsigned short* xt = (unsigned short*)ws;                        // 134217728 B
  unsigned short* aggw = (unsigned short*)(ws + 134217728ull);     // 9437184 B
  float* pooled = (float*)(ws + 134217728ull + 9437184ull);        // 16384 B
  float* aggb = (float*)(ws + 134217728ull + 9437184ull + 16384ull);  // 16384 B

  hipMemsetAsync(pooled, 0, 32 * 128 * sizeof(float), stream);
  prep_kernel<<<4096, 256, 0, stream>>>(x, xt, pooled);
  attn_agg_kernel<<<256, 256, 0, stream>>>(pooled, w1, b1, w2, b2, wgt, bias,
                                           aggw, aggb);
  conv_kernel<<<4096, 256, 0, stream>>>(xt, aggw, aggb, out);
}